// Round 2
// baseline (430.973 us; speedup 1.0000x reference)
//
#include <hip/hip_runtime.h>
#include <cstddef>

// Problem constants
#define NMOD   8
#define DEPTH_ 2
#define DIME   128
#define CCH    128   // channels
#define HH     32
#define WW     32
#define BB     16
#define HWPX   (HH*WW)

// Conv tiling
#define CO_TILE 8           // output channels per block
#define CI_TILE 4           // input channels staged per chunk
#define TROWS   34          // 32 + halo
#define TSTRIDE 36          // padded row stride, mult of 4 -> aligned b128 reads
#define NCHUNK  (CCH / CI_TILE)
#define PF_N    4           // float4 prefetch regs per thread per chunk

// ---------------------------------------------------------------------------
// Control: pooled mean -> ctl = pooled @ W_ctl^T + b_ctl -> argmin d2 vs emb
// Writes ctl, ctl_nearest into d_out tail, idx into workspace.
// ---------------------------------------------------------------------------
__global__ __launch_bounds__(256) void control_kernel(
    const float* __restrict__ x, const float* __restrict__ W_ctl,
    const float* __restrict__ b_ctl, const float* __restrict__ emb,
    float* __restrict__ ctl_out, float* __restrict__ ctln_out,
    int* __restrict__ idx_out)
{
    const int b    = blockIdx.x;
    const int tid  = threadIdx.x;
    const int lane = tid & 63;
    const int wv   = tid >> 6;

    __shared__ float pooled[CCH];
    __shared__ float ctlrow[DIME * DEPTH_];
    __shared__ float d2s[DEPTH_ * NMOD];
    __shared__ int   sidx[DEPTH_];

    // 1) pooled[c] = mean over 1024 px ; one wave per channel (coalesced)
    const float* xb = x + (size_t)b * CCH * HWPX;
    for (int c = wv; c < CCH; c += 4) {
        const float* xc = xb + (size_t)c * HWPX;
        float s = 0.f;
        for (int i = lane; i < HWPX; i += 64) s += xc[i];
        #pragma unroll
        for (int off = 32; off; off >>= 1) s += __shfl_xor(s, off, 64);
        if (lane == 0) pooled[c] = s * (1.0f / HWPX);
    }
    __syncthreads();

    // 2) ctl[j] = pooled . W_ctl[j,:] + b_ctl[j]  (j = 0..255)
    {
        const int j = tid;
        const float* wr = W_ctl + (size_t)j * CCH;
        float s = b_ctl[j];
        #pragma unroll 4
        for (int c = 0; c < CCH; ++c) s = fmaf(pooled[c], wr[c], s);
        ctlrow[j] = s;
        ctl_out[(size_t)b * (DIME * DEPTH_) + j] = s;
    }
    __syncthreads();

    // 3) d2[t][m] = sum_e (ctl[e,t] - emb[e,m])^2
    if (tid < DEPTH_ * NMOD) {
        const int t = tid >> 3, m = tid & 7;
        float s = 0.f;
        for (int e = 0; e < DIME; ++e) {
            float d = ctlrow[e * DEPTH_ + t] - emb[e * NMOD + m];
            s = fmaf(d, d, s);
        }
        d2s[t * NMOD + m] = s;
    }
    __syncthreads();

    // 4) argmin over m (first-min tie-break, matching jnp.argmin)
    if (tid < DEPTH_) {
        float best = d2s[tid * NMOD];
        int bi = 0;
        for (int m = 1; m < NMOD; ++m) {
            float d = d2s[tid * NMOD + m];
            if (d < best) { best = d; bi = m; }
        }
        sidx[tid] = bi;
        idx_out[b * DEPTH_ + tid] = bi;
    }
    __syncthreads();

    // 5) ctl_nearest[b,e,t] = emb[e, idx[b,t]]
    {
        const int e = tid >> 1, t = tid & 1;
        ctln_out[(size_t)b * (DIME * DEPTH_) + e * DEPTH_ + t] =
            emb[e * NMOD + sidx[t]];
    }
}

// ---------------------------------------------------------------------------
// Conv layer: per (b, co-group of 8), direct 3x3 SAME conv with the batch's
// selected expert only (8x less work than reference). +bias, ReLU.
// Register-prefetch double-buffers the input staging; TSTRIDE=36 gives
// aligned ds_read_b128 for the 6-wide input window.
// ---------------------------------------------------------------------------
__global__ __launch_bounds__(256) void conv_kernel(
    const float* __restrict__ in, const float* __restrict__ W_exp,
    const float* __restrict__ b_exp, const int* __restrict__ idx,
    int t, float* __restrict__ out)
{
    const int cog = blockIdx.x;            // 0..15
    const int b   = blockIdx.y;            // 0..15
    const int tid = threadIdx.x;
    const int m   = idx[b * DEPTH_ + t];
    const int co0 = cog * CO_TILE;

    // Weights for this co-group, transposed: [(ci*9+k)][co]   (36.0 KB)
    __shared__ float wlds[CCH * 9 * CO_TILE];
    // Zero-halo padded input chunk: [CI_TILE][34][36]         (19.1 KB)
    __shared__ float tile[CI_TILE * TROWS * TSTRIDE];

    // Stage + transpose weights once (one-time cost, ~4% of kernel)
    const float* wg = W_exp + ((size_t)m * CCH + co0) * (CCH * 9);
    for (int i = tid; i < CO_TILE * CCH * 9; i += 256) {
        int co = i / (CCH * 9);
        int r  = i - co * (CCH * 9);
        wlds[r * CO_TILE + co] = wg[(size_t)co * (CCH * 9) + r];
    }
    // Zero the tile once; borders stay zero forever (SAME padding)
    for (int i = tid; i < CI_TILE * TROWS * TSTRIDE; i += 256) tile[i] = 0.f;

    const int h  = tid >> 3;               // 0..31
    const int w4 = (tid & 7) * 4;          // 0,4,...,28

    float acc[4][CO_TILE];
    #pragma unroll
    for (int p = 0; p < 4; ++p)
        #pragma unroll
        for (int c = 0; c < CO_TILE; ++c) acc[p][c] = 0.f;

    const float* inb = in + (size_t)b * CCH * HWPX;

    // Prologue: prefetch chunk 0 into registers (coalesced float4)
    float4 pf[PF_N];
    #pragma unroll
    for (int k = 0; k < PF_N; ++k)
        pf[k] = *(const float4*)(inb + (size_t)(tid + k * 256) * 4);

    __syncthreads();   // weight staging + tile zeroing complete

    for (int ci0 = 0; ci0 < CCH; ci0 += CI_TILE) {
        // write prefetched chunk into interior of padded tile
        #pragma unroll
        for (int k = 0; k < PF_N; ++k) {
            const int q   = tid + k * 256;      // float4 index in chunk
            const int cil = q >> 8;             // 256 float4 per channel
            const int p4  = q & 255;
            const int hh  = p4 >> 3;            // (p4*4)>>5
            const int ww  = (p4 & 7) * 4;       // (p4*4)&31
            float* dst = &tile[cil * (TROWS * TSTRIDE) + (hh + 1) * TSTRIDE + (ww + 1)];
            dst[0] = pf[k].x; dst[1] = pf[k].y; dst[2] = pf[k].z; dst[3] = pf[k].w;
        }
        // issue next chunk's global loads now; consumed after next barrier,
        // so ~600cy HBM/L2 latency hides under this chunk's 2300cy of FMA
        if (ci0 + CI_TILE < CCH) {
            const float* src = inb + (size_t)(ci0 + CI_TILE) * HWPX;
            #pragma unroll
            for (int k = 0; k < PF_N; ++k)
                pf[k] = *(const float4*)(src + (size_t)(tid + k * 256) * 4);
        }
        __syncthreads();

        #pragma unroll
        for (int cil = 0; cil < CI_TILE; ++cil) {
            const float* trow = &tile[cil * (TROWS * TSTRIDE)];
            const float* wrow = &wlds[(size_t)(ci0 + cil) * 9 * CO_TILE];
            #pragma unroll
            for (int kh = 0; kh < 3; ++kh) {
                // input cols w4-1 .. w4+4 live at tile cols w4 .. w4+5
                // (h+kh)*36 + w4 is 16B-aligned -> b128 + b64
                const float* r = trow + (h + kh) * TSTRIDE + w4;
                const float4 a4 = *(const float4*)(r);
                const float2 a2 = *(const float2*)(r + 4);
                const float in6[6] = {a4.x, a4.y, a4.z, a4.w, a2.x, a2.y};
                #pragma unroll
                for (int kw = 0; kw < 3; ++kw) {
                    const float4 wa = *(const float4*)(wrow + (kh * 3 + kw) * CO_TILE);
                    const float4 wb = *(const float4*)(wrow + (kh * 3 + kw) * CO_TILE + 4);
                    #pragma unroll
                    for (int p = 0; p < 4; ++p) {
                        const float v = in6[p + kw];
                        acc[p][0] = fmaf(v, wa.x, acc[p][0]);
                        acc[p][1] = fmaf(v, wa.y, acc[p][1]);
                        acc[p][2] = fmaf(v, wa.z, acc[p][2]);
                        acc[p][3] = fmaf(v, wa.w, acc[p][3]);
                        acc[p][4] = fmaf(v, wb.x, acc[p][4]);
                        acc[p][5] = fmaf(v, wb.y, acc[p][5]);
                        acc[p][6] = fmaf(v, wb.z, acc[p][6]);
                        acc[p][7] = fmaf(v, wb.w, acc[p][7]);
                    }
                }
            }
        }
        __syncthreads();   // tile free for next chunk's writes
    }

    // Epilogue: +bias, ReLU, coalesced float4 stores
    const float* be = b_exp + (size_t)m * CCH + co0;
    float* ob = out + ((size_t)b * CCH + co0) * HWPX + h * WW + w4;
    #pragma unroll
    for (int c = 0; c < CO_TILE; ++c) {
        const float bv = be[c];
        float4 v;
        v.x = fmaxf(acc[0][c] + bv, 0.f);
        v.y = fmaxf(acc[1][c] + bv, 0.f);
        v.z = fmaxf(acc[2][c] + bv, 0.f);
        v.w = fmaxf(acc[3][c] + bv, 0.f);
        *(float4*)(ob + (size_t)c * HWPX) = v;
    }
}

// ---------------------------------------------------------------------------
extern "C" void kernel_launch(void* const* d_in, const int* in_sizes, int n_in,
                              void* d_out, int out_size, void* d_ws, size_t ws_size,
                              hipStream_t stream) {
    const float* x     = (const float*)d_in[0];
    const float* W_ctl = (const float*)d_in[1];
    const float* b_ctl = (const float*)d_in[2];
    const float* emb   = (const float*)d_in[3];
    const float* W_exp = (const float*)d_in[4];
    const float* b_exp = (const float*)d_in[5];

    float* out      = (float*)d_out;
    float* y_out    = out;                                      // (16,128,32,32)
    float* ctl_out  = out + (size_t)BB * CCH * HWPX;            // (16,128,2)
    float* ctln_out = ctl_out + BB * DIME * DEPTH_;             // (16,128,2)

    float* y1   = (float*)d_ws;                                 // 8 MB intermediate
    int*   idxp = (int*)((char*)d_ws + (size_t)BB * CCH * HWPX * sizeof(float));

    control_kernel<<<BB, 256, 0, stream>>>(x, W_ctl, b_ctl, emb,
                                           ctl_out, ctln_out, idxp);
    conv_kernel<<<dim3(CCH / CO_TILE, BB), 256, 0, stream>>>(
        x, W_exp, b_exp, idxp, 0, y1);
    conv_kernel<<<dim3(CCH / CO_TILE, BB), 256, 0, stream>>>(
        y1, W_exp, b_exp, idxp, 1, y_out);
}

// Round 3
// 273.818 us; speedup vs baseline: 1.5739x; 1.5739x over previous
//
#include <hip/hip_runtime.h>
#include <cstddef>

// Problem constants
#define NMOD   8
#define DEPTH_ 2
#define DIME   128
#define CCH    128   // channels
#define HH     32
#define WW     32
#define BB     16
#define HWPX   (HH*WW)

// Conv tiling
#define CO_TILE 8           // output channels per block
#define CI_TILE 4           // input channels staged per chunk
#define TROWS   34          // 32 + halo
#define TSTRIDE 36          // padded row stride, mult of 4 -> aligned b128 reads
#define PF_N    4           // float4 prefetch regs per thread per chunk

// ---------------------------------------------------------------------------
// Pool: pooled[b,c] = mean(x[b,c,:,:]).  One wave per channel, 512 blocks.
// ---------------------------------------------------------------------------
__global__ __launch_bounds__(256) void pool_kernel(
    const float* __restrict__ x, float* __restrict__ pooled)
{
    const int ch   = blockIdx.x * 4 + (threadIdx.x >> 6);   // 0..2047 = b*128+c
    const int lane = threadIdx.x & 63;
    const float* xc = x + (size_t)ch * HWPX;

    float4 s4 = {0.f, 0.f, 0.f, 0.f};
    #pragma unroll
    for (int k = 0; k < 4; ++k) {
        const float4 v = *(const float4*)(xc + (size_t)(lane + k * 64) * 4);
        s4.x += v.x; s4.y += v.y; s4.z += v.z; s4.w += v.w;
    }
    float s = (s4.x + s4.y) + (s4.z + s4.w);
    #pragma unroll
    for (int off = 32; off; off >>= 1) s += __shfl_xor(s, off, 64);
    if (lane == 0) pooled[ch] = s * (1.0f / HWPX);
}

// ---------------------------------------------------------------------------
// Ctl: ctl = pooled @ W_ctl^T + b_ctl ; d2/argmin vs emb ; ctl_nearest.
// One block per batch, thread j owns output j (32 independent float4 loads).
// ---------------------------------------------------------------------------
__global__ __launch_bounds__(256) void ctl_kernel(
    const float* __restrict__ pooled, const float* __restrict__ W_ctl,
    const float* __restrict__ b_ctl, const float* __restrict__ emb,
    float* __restrict__ ctl_out, float* __restrict__ ctln_out,
    int* __restrict__ idx_out)
{
    const int b   = blockIdx.x;
    const int tid = threadIdx.x;

    __shared__ float pld[CCH];
    __shared__ float ctlrow[DIME * DEPTH_];
    __shared__ float d2s[DEPTH_ * NMOD];
    __shared__ int   sidx[DEPTH_];

    if (tid < CCH / 4)
        ((float4*)pld)[tid] = ((const float4*)(pooled + (size_t)b * CCH))[tid];
    __syncthreads();

    // ctl[j] = pooled . W_ctl[j,:] + b_ctl[j]; 32 independent float4 loads
    {
        const float4* wr = (const float4*)(W_ctl + (size_t)tid * CCH);
        const float4* pv = (const float4*)pld;
        float a0 = 0.f, a1 = 0.f, a2 = 0.f, a3 = 0.f;
        #pragma unroll
        for (int k = 0; k < 32; k += 4) {
            const float4 w0 = wr[k + 0], p0 = pv[k + 0];
            const float4 w1 = wr[k + 1], p1 = pv[k + 1];
            const float4 w2 = wr[k + 2], p2 = pv[k + 2];
            const float4 w3 = wr[k + 3], p3 = pv[k + 3];
            a0 = fmaf(w0.x, p0.x, fmaf(w0.y, p0.y, fmaf(w0.z, p0.z, fmaf(w0.w, p0.w, a0))));
            a1 = fmaf(w1.x, p1.x, fmaf(w1.y, p1.y, fmaf(w1.z, p1.z, fmaf(w1.w, p1.w, a1))));
            a2 = fmaf(w2.x, p2.x, fmaf(w2.y, p2.y, fmaf(w2.z, p2.z, fmaf(w2.w, p2.w, a2))));
            a3 = fmaf(w3.x, p3.x, fmaf(w3.y, p3.y, fmaf(w3.z, p3.z, fmaf(w3.w, p3.w, a3))));
        }
        const float s = b_ctl[tid] + ((a0 + a1) + (a2 + a3));
        ctlrow[tid] = s;
        ctl_out[(size_t)b * (DIME * DEPTH_) + tid] = s;
    }
    __syncthreads();

    // d2[t][m]: 16 (t,m) pairs x 16 lanes, each lane sums 8 e's, shfl-reduce
    {
        const int p = tid >> 4;          // 0..15 -> (t,m)
        const int sub = tid & 15;
        const int t = p >> 3, mm = p & 7;
        float s = 0.f;
        #pragma unroll
        for (int k = 0; k < 8; ++k) {
            const int e = sub * 8 + k;
            const float d = ctlrow[e * DEPTH_ + t] - emb[e * NMOD + mm];
            s = fmaf(d, d, s);
        }
        #pragma unroll
        for (int off = 8; off; off >>= 1) s += __shfl_xor(s, off, 16);
        if (sub == 0) d2s[p] = s;
    }
    __syncthreads();

    // argmin over m (first-min tie-break, matching jnp.argmin)
    if (tid < DEPTH_) {
        float best = d2s[tid * NMOD];
        int bi = 0;
        for (int m = 1; m < NMOD; ++m) {
            const float d = d2s[tid * NMOD + m];
            if (d < best) { best = d; bi = m; }
        }
        sidx[tid] = bi;
        idx_out[b * DEPTH_ + tid] = bi;
    }
    __syncthreads();

    // ctl_nearest[b,e,t] = emb[e, idx[b,t]]
    {
        const int e = tid >> 1, t = tid & 1;
        ctln_out[(size_t)b * (DIME * DEPTH_) + e * DEPTH_ + t] =
            emb[e * NMOD + sidx[t]];
    }
}

// ---------------------------------------------------------------------------
// Conv layer: per (b, co-group of 8), direct 3x3 SAME conv with the batch's
// selected expert only (8x less work than reference). +bias, ReLU.
// Register-prefetch double-buffers the input staging; TSTRIDE=36 gives
// aligned ds_read_b128 for the 6-wide input window.
// ---------------------------------------------------------------------------
__global__ __launch_bounds__(256) void conv_kernel(
    const float* __restrict__ in, const float* __restrict__ W_exp,
    const float* __restrict__ b_exp, const int* __restrict__ idx,
    int t, float* __restrict__ out)
{
    const int cog = blockIdx.x;            // 0..15
    const int b   = blockIdx.y;            // 0..15
    const int tid = threadIdx.x;
    // idx is uniform per block: force SGPR so all weight addressing is scalar
    const int m   = __builtin_amdgcn_readfirstlane(idx[b * DEPTH_ + t]);
    const int co0 = cog * CO_TILE;

    // Weights for this co-group, transposed: [(ci*9+k)][co]   (36.0 KB)
    __shared__ float wlds[CCH * 9 * CO_TILE];
    // Zero-halo padded input chunk: [CI_TILE][34][36]         (19.1 KB)
    __shared__ float tile[CI_TILE * TROWS * TSTRIDE];

    // Stage + transpose weights once (one-time cost)
    const float* wg = W_exp + ((size_t)m * CCH + co0) * (CCH * 9);
    for (int i = tid; i < CO_TILE * CCH * 9; i += 256) {
        int co = i / (CCH * 9);
        int r  = i - co * (CCH * 9);
        wlds[r * CO_TILE + co] = wg[(size_t)co * (CCH * 9) + r];
    }
    // Zero the tile once; borders stay zero forever (SAME padding)
    for (int i = tid; i < CI_TILE * TROWS * TSTRIDE; i += 256) tile[i] = 0.f;

    const int h  = tid >> 3;               // 0..31
    const int w4 = (tid & 7) * 4;          // 0,4,...,28

    float acc[4][CO_TILE];
    #pragma unroll
    for (int p = 0; p < 4; ++p)
        #pragma unroll
        for (int c = 0; c < CO_TILE; ++c) acc[p][c] = 0.f;

    const float* inb = in + (size_t)b * CCH * HWPX;

    // Prologue: prefetch chunk 0 into registers (coalesced float4)
    float4 pf[PF_N];
    #pragma unroll
    for (int k = 0; k < PF_N; ++k)
        pf[k] = *(const float4*)(inb + (size_t)(tid + k * 256) * 4);

    __syncthreads();   // weight staging + tile zeroing complete

    for (int ci0 = 0; ci0 < CCH; ci0 += CI_TILE) {
        // write prefetched chunk into interior of padded tile
        #pragma unroll
        for (int k = 0; k < PF_N; ++k) {
            const int q   = tid + k * 256;      // float4 index in chunk
            const int cil = q >> 8;             // 256 float4 per channel
            const int p4  = q & 255;
            const int hh  = p4 >> 3;            // (p4*4)>>5
            const int ww  = (p4 & 7) * 4;       // (p4*4)&31
            float* dst = &tile[cil * (TROWS * TSTRIDE) + (hh + 1) * TSTRIDE + (ww + 1)];
            dst[0] = pf[k].x; dst[1] = pf[k].y; dst[2] = pf[k].z; dst[3] = pf[k].w;
        }
        // issue next chunk's global loads now; consumed after next barrier,
        // so ~600cy HBM/L2 latency hides under this chunk's 2300cy of FMA
        if (ci0 + CI_TILE < CCH) {
            const float* src = inb + (size_t)(ci0 + CI_TILE) * HWPX;
            #pragma unroll
            for (int k = 0; k < PF_N; ++k)
                pf[k] = *(const float4*)(src + (size_t)(tid + k * 256) * 4);
        }
        __syncthreads();

        #pragma unroll
        for (int cil = 0; cil < CI_TILE; ++cil) {
            const float* trow = &tile[cil * (TROWS * TSTRIDE)];
            const float* wrow = &wlds[(size_t)(ci0 + cil) * 9 * CO_TILE];
            #pragma unroll
            for (int kh = 0; kh < 3; ++kh) {
                // input cols w4-1 .. w4+4 live at tile cols w4 .. w4+5
                // (h+kh)*36 + w4 is 16B-aligned -> b128 + b64
                const float* r = trow + (h + kh) * TSTRIDE + w4;
                const float4 a4 = *(const float4*)(r);
                const float2 a2 = *(const float2*)(r + 4);
                const float in6[6] = {a4.x, a4.y, a4.z, a4.w, a2.x, a2.y};
                #pragma unroll
                for (int kw = 0; kw < 3; ++kw) {
                    const float4 wa = *(const float4*)(wrow + (kh * 3 + kw) * CO_TILE);
                    const float4 wb = *(const float4*)(wrow + (kh * 3 + kw) * CO_TILE + 4);
                    #pragma unroll
                    for (int p = 0; p < 4; ++p) {
                        const float v = in6[p + kw];
                        acc[p][0] = fmaf(v, wa.x, acc[p][0]);
                        acc[p][1] = fmaf(v, wa.y, acc[p][1]);
                        acc[p][2] = fmaf(v, wa.z, acc[p][2]);
                        acc[p][3] = fmaf(v, wa.w, acc[p][3]);
                        acc[p][4] = fmaf(v, wb.x, acc[p][4]);
                        acc[p][5] = fmaf(v, wb.y, acc[p][5]);
                        acc[p][6] = fmaf(v, wb.z, acc[p][6]);
                        acc[p][7] = fmaf(v, wb.w, acc[p][7]);
                    }
                }
            }
        }
        __syncthreads();   // tile free for next chunk's writes
    }

    // Epilogue: +bias, ReLU, coalesced float4 stores
    const float* be = b_exp + (size_t)m * CCH + co0;
    float* ob = out + ((size_t)b * CCH + co0) * HWPX + h * WW + w4;
    #pragma unroll
    for (int c = 0; c < CO_TILE; ++c) {
        const float bv = be[c];
        float4 v;
        v.x = fmaxf(acc[0][c] + bv, 0.f);
        v.y = fmaxf(acc[1][c] + bv, 0.f);
        v.z = fmaxf(acc[2][c] + bv, 0.f);
        v.w = fmaxf(acc[3][c] + bv, 0.f);
        *(float4*)(ob + (size_t)c * HWPX) = v;
    }
}

// ---------------------------------------------------------------------------
extern "C" void kernel_launch(void* const* d_in, const int* in_sizes, int n_in,
                              void* d_out, int out_size, void* d_ws, size_t ws_size,
                              hipStream_t stream) {
    const float* x     = (const float*)d_in[0];
    const float* W_ctl = (const float*)d_in[1];
    const float* b_ctl = (const float*)d_in[2];
    const float* emb   = (const float*)d_in[3];
    const float* W_exp = (const float*)d_in[4];
    const float* b_exp = (const float*)d_in[5];

    float* out      = (float*)d_out;
    float* y_out    = out;                                      // (16,128,32,32)
    float* ctl_out  = out + (size_t)BB * CCH * HWPX;            // (16,128,2)
    float* ctln_out = ctl_out + BB * DIME * DEPTH_;             // (16,128,2)

    float* y1     = (float*)d_ws;                               // 8 MB intermediate
    int*   idxp   = (int*)((char*)d_ws + (size_t)BB * CCH * HWPX * sizeof(float));
    float* pooled = (float*)((char*)idxp + 128);                // 16x128 floats

    pool_kernel<<<(BB * CCH) / 4, 256, 0, stream>>>(x, pooled);
    ctl_kernel<<<BB, 256, 0, stream>>>(pooled, W_ctl, b_ctl, emb,
                                       ctl_out, ctln_out, idxp);
    conv_kernel<<<dim3(CCH / CO_TILE, BB), 256, 0, stream>>>(
        x, W_exp, b_exp, idxp, 0, y1);
    conv_kernel<<<dim3(CCH / CO_TILE, BB), 256, 0, stream>>>(
        y1, W_exp, b_exp, idxp, 1, y_out);
}

// Round 4
// 240.403 us; speedup vs baseline: 1.7927x; 1.1390x over previous
//
#include <hip/hip_runtime.h>
#include <cstddef>

// Problem constants
#define NMOD   8
#define DEPTH_ 2
#define DIME   128
#define CCH    128   // channels
#define HH     32
#define WW     32
#define BB     16
#define HWPX   (HH*WW)

// Conv tiling: CO_TILE=4 -> 37.4 KB LDS -> 2 blocks/CU (2 waves/SIMD)
#define CO_TILE 4           // output channels per block
#define CI_TILE 4           // input channels staged per chunk
#define TROWS   34          // 32 + halo
#define TSTRIDE 36          // padded row stride, mult of 4 -> aligned b128 reads
#define PF_N    4           // float4 prefetch regs per thread per chunk

// ---------------------------------------------------------------------------
// Pool: pooled[b,c] = mean(x[b,c,:,:]).  One wave per channel, 512 blocks.
// ---------------------------------------------------------------------------
__global__ __launch_bounds__(256) void pool_kernel(
    const float* __restrict__ x, float* __restrict__ pooled)
{
    const int ch   = blockIdx.x * 4 + (threadIdx.x >> 6);   // 0..2047 = b*128+c
    const int lane = threadIdx.x & 63;
    const float* xc = x + (size_t)ch * HWPX;

    float4 s4 = {0.f, 0.f, 0.f, 0.f};
    #pragma unroll
    for (int k = 0; k < 4; ++k) {
        const float4 v = *(const float4*)(xc + (size_t)(lane + k * 64) * 4);
        s4.x += v.x; s4.y += v.y; s4.z += v.z; s4.w += v.w;
    }
    float s = (s4.x + s4.y) + (s4.z + s4.w);
    #pragma unroll
    for (int off = 32; off; off >>= 1) s += __shfl_xor(s, off, 64);
    if (lane == 0) pooled[ch] = s * (1.0f / HWPX);
}

// ---------------------------------------------------------------------------
// Ctl: ctl = pooled @ W_ctl^T + b_ctl ; d2/argmin vs emb ; ctl_nearest.
// ---------------------------------------------------------------------------
__global__ __launch_bounds__(256) void ctl_kernel(
    const float* __restrict__ pooled, const float* __restrict__ W_ctl,
    const float* __restrict__ b_ctl, const float* __restrict__ emb,
    float* __restrict__ ctl_out, float* __restrict__ ctln_out,
    int* __restrict__ idx_out)
{
    const int b   = blockIdx.x;
    const int tid = threadIdx.x;

    __shared__ float pld[CCH];
    __shared__ float ctlrow[DIME * DEPTH_];
    __shared__ float d2s[DEPTH_ * NMOD];
    __shared__ int   sidx[DEPTH_];

    if (tid < CCH / 4)
        ((float4*)pld)[tid] = ((const float4*)(pooled + (size_t)b * CCH))[tid];
    __syncthreads();

    // ctl[j] = pooled . W_ctl[j,:] + b_ctl[j]; 32 independent float4 loads
    {
        const float4* wr = (const float4*)(W_ctl + (size_t)tid * CCH);
        const float4* pv = (const float4*)pld;
        float a0 = 0.f, a1 = 0.f, a2 = 0.f, a3 = 0.f;
        #pragma unroll
        for (int k = 0; k < 32; k += 4) {
            const float4 w0 = wr[k + 0], p0 = pv[k + 0];
            const float4 w1 = wr[k + 1], p1 = pv[k + 1];
            const float4 w2 = wr[k + 2], p2 = pv[k + 2];
            const float4 w3 = wr[k + 3], p3 = pv[k + 3];
            a0 = fmaf(w0.x, p0.x, fmaf(w0.y, p0.y, fmaf(w0.z, p0.z, fmaf(w0.w, p0.w, a0))));
            a1 = fmaf(w1.x, p1.x, fmaf(w1.y, p1.y, fmaf(w1.z, p1.z, fmaf(w1.w, p1.w, a1))));
            a2 = fmaf(w2.x, p2.x, fmaf(w2.y, p2.y, fmaf(w2.z, p2.z, fmaf(w2.w, p2.w, a2))));
            a3 = fmaf(w3.x, p3.x, fmaf(w3.y, p3.y, fmaf(w3.z, p3.z, fmaf(w3.w, p3.w, a3))));
        }
        const float s = b_ctl[tid] + ((a0 + a1) + (a2 + a3));
        ctlrow[tid] = s;
        ctl_out[(size_t)b * (DIME * DEPTH_) + tid] = s;
    }
    __syncthreads();

    // d2[t][m]: 16 (t,m) pairs x 16 lanes, each lane sums 8 e's, shfl-reduce
    {
        const int p = tid >> 4;          // 0..15 -> (t,m)
        const int sub = tid & 15;
        const int t = p >> 3, mm = p & 7;
        float s = 0.f;
        #pragma unroll
        for (int k = 0; k < 8; ++k) {
            const int e = sub * 8 + k;
            const float d = ctlrow[e * DEPTH_ + t] - emb[e * NMOD + mm];
            s = fmaf(d, d, s);
        }
        #pragma unroll
        for (int off = 8; off; off >>= 1) s += __shfl_xor(s, off, 16);
        if (sub == 0) d2s[p] = s;
    }
    __syncthreads();

    // argmin over m (first-min tie-break, matching jnp.argmin)
    if (tid < DEPTH_) {
        float best = d2s[tid * NMOD];
        int bi = 0;
        for (int m = 1; m < NMOD; ++m) {
            const float d = d2s[tid * NMOD + m];
            if (d < best) { best = d; bi = m; }
        }
        sidx[tid] = bi;
        idx_out[b * DEPTH_ + tid] = bi;
    }
    __syncthreads();

    // ctl_nearest[b,e,t] = emb[e, idx[b,t]]
    {
        const int e = tid >> 1, t = tid & 1;
        ctln_out[(size_t)b * (DIME * DEPTH_) + e * DEPTH_ + t] =
            emb[e * NMOD + sidx[t]];
    }
}

// ---------------------------------------------------------------------------
// Conv layer: per (b, co-group of 4), direct 3x3 SAME conv with the batch's
// selected expert only. +bias, ReLU. 512 blocks -> 2 blocks/CU so ds_read
// latency and barrier drains hide under the other block's FMAs.
// ---------------------------------------------------------------------------
__global__ __launch_bounds__(256, 2) void conv_kernel(
    const float* __restrict__ in, const float* __restrict__ W_exp,
    const float* __restrict__ b_exp, const int* __restrict__ idx,
    int t, float* __restrict__ out)
{
    const int cog = blockIdx.x;            // 0..31
    const int b   = blockIdx.y;            // 0..15
    const int tid = threadIdx.x;
    // idx is uniform per block: force SGPR so all weight addressing is scalar
    const int m   = __builtin_amdgcn_readfirstlane(idx[b * DEPTH_ + t]);
    const int co0 = cog * CO_TILE;

    // Weights for this co-group, transposed: [(ci*9+k)][co]   (18.0 KB)
    __shared__ float wlds[CCH * 9 * CO_TILE];
    // Zero-halo padded input chunk: [CI_TILE][34][36]         (19.1 KB)
    __shared__ float tile[CI_TILE * TROWS * TSTRIDE];

    // Stage + transpose weights once (one-time cost)
    const float* wg = W_exp + ((size_t)m * CCH + co0) * (CCH * 9);
    for (int i = tid; i < CO_TILE * CCH * 9; i += 256) {
        int co = i / (CCH * 9);
        int r  = i - co * (CCH * 9);
        wlds[r * CO_TILE + co] = wg[(size_t)co * (CCH * 9) + r];
    }
    // Zero the tile once; borders stay zero forever (SAME padding)
    for (int i = tid; i < CI_TILE * TROWS * TSTRIDE; i += 256) tile[i] = 0.f;

    const int h  = tid >> 3;               // 0..31
    const int w4 = (tid & 7) * 4;          // 0,4,...,28

    float acc[4][CO_TILE];
    #pragma unroll
    for (int p = 0; p < 4; ++p)
        #pragma unroll
        for (int c = 0; c < CO_TILE; ++c) acc[p][c] = 0.f;

    const float* inb = in + (size_t)b * CCH * HWPX;

    // Prologue: prefetch chunk 0 into registers (coalesced float4)
    float4 pf[PF_N];
    #pragma unroll
    for (int k = 0; k < PF_N; ++k)
        pf[k] = *(const float4*)(inb + (size_t)(tid + k * 256) * 4);

    __syncthreads();   // weight staging + tile zeroing complete

    for (int ci0 = 0; ci0 < CCH; ci0 += CI_TILE) {
        // write prefetched chunk into interior of padded tile
        #pragma unroll
        for (int k = 0; k < PF_N; ++k) {
            const int q   = tid + k * 256;      // float4 index in chunk
            const int cil = q >> 8;             // 256 float4 per channel
            const int p4  = q & 255;
            const int hh  = p4 >> 3;
            const int ww  = (p4 & 7) * 4;
            float* dst = &tile[cil * (TROWS * TSTRIDE) + (hh + 1) * TSTRIDE + (ww + 1)];
            dst[0] = pf[k].x; dst[1] = pf[k].y; dst[2] = pf[k].z; dst[3] = pf[k].w;
        }
        // issue next chunk's global loads now; consumed after next barrier
        if (ci0 + CI_TILE < CCH) {
            const float* src = inb + (size_t)(ci0 + CI_TILE) * HWPX;
            #pragma unroll
            for (int k = 0; k < PF_N; ++k)
                pf[k] = *(const float4*)(src + (size_t)(tid + k * 256) * 4);
        }
        __syncthreads();

        #pragma unroll
        for (int cil = 0; cil < CI_TILE; ++cil) {
            const float* trow = &tile[cil * (TROWS * TSTRIDE)];
            const float* wrow = &wlds[(size_t)(ci0 + cil) * 9 * CO_TILE];
            #pragma unroll
            for (int kh = 0; kh < 3; ++kh) {
                // input cols w4-1 .. w4+4 live at tile cols w4 .. w4+5
                // (h+kh)*36 + w4 is 16B-aligned -> b128 + b64
                const float* r = trow + (h + kh) * TSTRIDE + w4;
                const float4 a4 = *(const float4*)(r);
                const float2 a2 = *(const float2*)(r + 4);
                const float in6[6] = {a4.x, a4.y, a4.z, a4.w, a2.x, a2.y};
                #pragma unroll
                for (int kw = 0; kw < 3; ++kw) {
                    const float4 wa = *(const float4*)(wrow + (kh * 3 + kw) * CO_TILE);
                    #pragma unroll
                    for (int p = 0; p < 4; ++p) {
                        const float v = in6[p + kw];
                        acc[p][0] = fmaf(v, wa.x, acc[p][0]);
                        acc[p][1] = fmaf(v, wa.y, acc[p][1]);
                        acc[p][2] = fmaf(v, wa.z, acc[p][2]);
                        acc[p][3] = fmaf(v, wa.w, acc[p][3]);
                    }
                }
            }
        }
        __syncthreads();   // tile free for next chunk's writes
    }

    // Epilogue: +bias, ReLU, coalesced float4 stores
    const float* be = b_exp + (size_t)m * CCH + co0;
    float* ob = out + ((size_t)b * CCH + co0) * HWPX + h * WW + w4;
    #pragma unroll
    for (int c = 0; c < CO_TILE; ++c) {
        const float bv = be[c];
        float4 v;
        v.x = fmaxf(acc[0][c] + bv, 0.f);
        v.y = fmaxf(acc[1][c] + bv, 0.f);
        v.z = fmaxf(acc[2][c] + bv, 0.f);
        v.w = fmaxf(acc[3][c] + bv, 0.f);
        *(float4*)(ob + (size_t)c * HWPX) = v;
    }
}

// ---------------------------------------------------------------------------
extern "C" void kernel_launch(void* const* d_in, const int* in_sizes, int n_in,
                              void* d_out, int out_size, void* d_ws, size_t ws_size,
                              hipStream_t stream) {
    const float* x     = (const float*)d_in[0];
    const float* W_ctl = (const float*)d_in[1];
    const float* b_ctl = (const float*)d_in[2];
    const float* emb   = (const float*)d_in[3];
    const float* W_exp = (const float*)d_in[4];
    const float* b_exp = (const float*)d_in[5];

    float* out      = (float*)d_out;
    float* y_out    = out;                                      // (16,128,32,32)
    float* ctl_out  = out + (size_t)BB * CCH * HWPX;            // (16,128,2)
    float* ctln_out = ctl_out + BB * DIME * DEPTH_;             // (16,128,2)

    float* y1     = (float*)d_ws;                               // 8 MB intermediate
    int*   idxp   = (int*)((char*)d_ws + (size_t)BB * CCH * HWPX * sizeof(float));
    float* pooled = (float*)((char*)idxp + 128);                // 16x128 floats

    pool_kernel<<<(BB * CCH) / 4, 256, 0, stream>>>(x, pooled);
    ctl_kernel<<<BB, 256, 0, stream>>>(pooled, W_ctl, b_ctl, emb,
                                       ctl_out, ctln_out, idxp);
    conv_kernel<<<dim3(CCH / CO_TILE, BB), 256, 0, stream>>>(
        x, W_exp, b_exp, idxp, 0, y1);
    conv_kernel<<<dim3(CCH / CO_TILE, BB), 256, 0, stream>>>(
        y1, W_exp, b_exp, idxp, 1, y_out);
}